// Round 6
// baseline (483.888 us; speedup 1.0000x reference)
//
#include <hip/hip_runtime.h>
#include <hip/hip_bf16.h>

#define N_NODES 30000
#define F_INLEN 500
#define HID 16
#define OUTC 3
#define NEDGE 960000
#define EPB (NEDGE / N_NODES)   // 32 edges per conv block
#define YPITCH 20               // shorts per row: 40B -> conflict-free, 8B aligned
#define NB 512                  // persistent blocks for gcn_mega (2 per CU)
#define NPB 59                  // nodes per block: 512*59 = 30208 >= 30000
#define EPB2 (NEDGE / NB)       // 1875 edges per block

typedef float  f32x4 __attribute__((ext_vector_type(4)));
typedef float  f32x2 __attribute__((ext_vector_type(2)));
typedef short  s16x8 __attribute__((ext_vector_type(8)));

static __device__ __forceinline__ unsigned short f2bf(float f) {
    unsigned int u = __float_as_uint(f);
    unsigned int r = (u + 0x7fffu + ((u >> 16) & 1u)) >> 16;
    return (unsigned short)r;
}
static __device__ __forceinline__ unsigned int pack_bf16x2(float v0, float v1) {
#if __has_builtin(__builtin_amdgcn_cvt_pk_bf16_f32)
    typedef __bf16 bf16x2_t __attribute__((ext_vector_type(2)));
    union { bf16x2_t v; unsigned int u; } cv;
    cv.v = __builtin_amdgcn_cvt_pk_bf16_f32(v0, v1);
    return cv.u;
#else
    return (unsigned int)f2bf(v0) | (((unsigned int)f2bf(v1)) << 16);
#endif
}

// ---------------- K0: B-fragments + zero degi + zero barriers ----------------
__global__ void setup_kernel(const float* __restrict__ w2, short* __restrict__ bfragsG,
                             int* __restrict__ degi, int* __restrict__ bar)
{
    const int tid = threadIdx.x;
    const int gid = blockIdx.x * 256 + tid;
    if (gid < N_NODES) degi[gid] = 0;
    if (gid < 8) bar[gid] = 0;
    if (blockIdx.x == 0 && tid < 64) {
        const int n16 = tid & 15, q = tid >> 4;
#pragma unroll
        for (int j = 0; j < 8; j++) {
            {   // s = 0
                const int c = q * 8 + j;
                const int t = c >> 4, i = c & 15;
                bfragsG[tid * 16 + j] = (short)f2bf(w2[n16 * 48 + i * 3 + t]);
            }
            {   // s = 1 (zero for c >= 48)
                const int c = 32 + q * 8 + j;
                short v = 0;
                if (c < 48) { const int t = c >> 4, i = c & 15; v = (short)f2bf(w2[n16 * 48 + i * 3 + t]); }
                bfragsG[tid * 16 + 8 + j] = v;
            }
        }
    }
}

// ---------------- K1: conv1 -> relu -> conv2(MFMA) -> relu -> max  (+deg atomics)
// (unchanged from R5: proven at ~107 us)
__global__ __launch_bounds__(256, 7) void conv_fused(
    const float* __restrict__ x,
    const float* __restrict__ w1, const float* __restrict__ b1,
    const float* __restrict__ b2, const short* __restrict__ bfragsG,
    const int* __restrict__ dst, int* __restrict__ degi,
    float* __restrict__ h0)
{
    __shared__ __align__(16) float xp[502];
    __shared__ __align__(16) unsigned short yh[516 * YPITCH];
    __shared__ float red[64];

    const int tid  = threadIdx.x;
    const int node = blockIdx.x;
    const int lane = tid & 63;
    const int wave = tid >> 6;
    const int n16  = lane & 15;
    const int q    = lane >> 4;

    if (tid < EPB) {
        const int e = node * EPB + tid;
        atomicAdd(&degi[dst[e]], 1);
    }

    if (tid == 0) { xp[0] = 0.f; xp[501] = 0.f; }
    if (tid < 125) {
        const float4 v = ((const float4*)(x + (long long)node * F_INLEN))[tid];
        xp[4 * tid + 1] = v.x; xp[4 * tid + 2] = v.y;
        xp[4 * tid + 3] = v.z; xp[4 * tid + 4] = v.w;
    }
    {
        const int ri = tid >> 4;
        const int row = (ri == 0) ? 0 : (500 + ri);
        yh[row * YPITCH + (tid & 15)] = 0;
    }
    const s16x8* bfp = (const s16x8*)(bfragsG + lane * 16);
    const s16x8 bh0 = bfp[0], bh1 = bfp[1];

    f32x2 wt0[8], wt1[8], wt2[8], bb[8];
#pragma unroll
    for (int cp = 0; cp < 8; cp++) {
        const int c0 = 2 * cp, c1 = 2 * cp + 1;
        wt0[cp] = (f32x2){w1[c0 * 3 + 0], w1[c1 * 3 + 0]};
        wt1[cp] = (f32x2){w1[c0 * 3 + 1], w1[c1 * 3 + 1]};
        wt2[cp] = (f32x2){w1[c0 * 3 + 2], w1[c1 * 3 + 2]};
        bb[cp]  = (f32x2){b1[c0], b1[c1]};
    }
    __syncthreads();

    for (int p = tid; p < 500; p += 256) {
        const float x0 = xp[p], x1 = xp[p + 1], x2 = xp[p + 2];
        const f32x2 xv0 = {x0, x0}, xv1 = {x1, x1}, xv2 = {x2, x2};
        const f32x2 zero = {0.f, 0.f};
        unsigned int hp[8];
#pragma unroll
        for (int cp = 0; cp < 8; cp++) {
            f32x2 a = bb[cp];
            a = __builtin_elementwise_fma(wt0[cp], xv0, a);
            a = __builtin_elementwise_fma(wt1[cp], xv1, a);
            a = __builtin_elementwise_fma(wt2[cp], xv2, a);
            a = __builtin_elementwise_max(a, zero);
            hp[cp] = pack_bf16x2(a[0], a[1]);
        }
        uint2* d = (uint2*)&yh[(p + 1) * YPITCH];
        d[0] = make_uint2(hp[0], hp[1]);
        d[1] = make_uint2(hp[2], hp[3]);
        d[2] = make_uint2(hp[4], hp[5]);
        d[3] = make_uint2(hp[6], hp[7]);
    }
    __syncthreads();

    struct S8 { short4 lo, hi; };
    float mx0 = -3.0e38f, mx1 = -3.0e38f, mx2 = -3.0e38f, mx3 = -3.0e38f;
#pragma unroll
    for (int it = 0; it < 8; it++) {
        const int tile = wave * 8 + it;
        const int p0 = tile * 16 + n16;
        const int cA = (q & 1) * 8;
        const int rA = p0 + (q >> 1);
        const int rB = p0 + 2 + (q >> 1);
        S8 t0, t1;
        t0.lo = *(const short4*)&yh[rA * YPITCH + cA];
        t0.hi = *(const short4*)&yh[rA * YPITCH + cA + 4];
        t1.lo = *(const short4*)&yh[rB * YPITCH + cA];
        t1.hi = *(const short4*)&yh[rB * YPITCH + cA + 4];
        const s16x8 ah0 = *(const s16x8*)&t0;
        const s16x8 ah1 = *(const s16x8*)&t1;
        f32x4 acc = {0.f, 0.f, 0.f, 0.f};
        acc = __builtin_amdgcn_mfma_f32_16x16x32_bf16(ah0, bh0, acc, 0, 0, 0);
        acc = __builtin_amdgcn_mfma_f32_16x16x32_bf16(ah1, bh1, acc, 0, 0, 0);
        const int rb = tile * 16 + q * 4;
        if (rb + 0 < 500) mx0 = fmaxf(mx0, acc[0]);
        if (rb + 1 < 500) mx1 = fmaxf(mx1, acc[1]);
        if (rb + 2 < 500) mx2 = fmaxf(mx2, acc[2]);
        if (rb + 3 < 500) mx3 = fmaxf(mx3, acc[3]);
    }
    float m = fmaxf(fmaxf(mx0, mx1), fmaxf(mx2, mx3));
    m = fmaxf(m, __shfl_xor(m, 16));
    m = fmaxf(m, __shfl_xor(m, 32));
    if (lane < 16) red[wave * 16 + lane] = m;
    __syncthreads();
    if (tid < 16) {
        const float mm = fmaxf(fmaxf(red[tid], red[16 + tid]), fmaxf(red[32 + tid], red[48 + tid]));
        h0[node * HID + tid] = fmaxf(mm + b2[tid], 0.f);
    }
}

// ---------------- grid-wide barrier (device-scope, all blocks co-resident) ---
static __device__ __forceinline__ void gridbar(int* __restrict__ bar, int idx)
{
    __syncthreads();
    if (threadIdx.x == 0) {
        __hip_atomic_fetch_add(&bar[idx], 1, __ATOMIC_ACQ_REL, __HIP_MEMORY_SCOPE_AGENT);
        while (__hip_atomic_load(&bar[idx], __ATOMIC_ACQUIRE, __HIP_MEMORY_SCOPE_AGENT) < NB)
            __builtin_amdgcn_s_sleep(1);
    }
    __syncthreads();
}

// ---------------- K2: fused GCN phase: scan -> CSR -> gather1 -> gather2 -----
__global__ __launch_bounds__(256, 2) void gcn_mega(
    const int* __restrict__ src, const int* __restrict__ dst,
    const int* __restrict__ degi, const float* __restrict__ h0,
    float* __restrict__ h0p, float* __restrict__ dinv,
    int* __restrict__ rowptr, int* __restrict__ fill, int* __restrict__ srcb,
    const float* __restrict__ W1, const float* __restrict__ b1g,
    const float* __restrict__ W2, const float* __restrict__ b2g,
    float* __restrict__ t2p4, float* __restrict__ out,
    int* __restrict__ gsum, int* __restrict__ bar)
{
    __shared__ float w1s[256];
    __shared__ float w2s[48];
    __shared__ float b1s[16];
    __shared__ float dinvS[NPB];

    const int tid  = threadIdx.x;
    const int b    = blockIdx.x;
    const int lane = tid & 63;
    const int wave = tid >> 6;
    const int base = b * NPB;
    const int cnt  = (base < N_NODES) ? ((N_NODES - base < NPB) ? (N_NODES - base) : NPB) : 0;

    w1s[tid] = W1[tid];
    if (tid < 48) w2s[tid] = W2[tid];
    if (tid < 16) b1s[tid] = b1g[tid];

    // ---- B1: block-local degree scan ----
    int dg = 0, incl = 0;
    if (wave == 0) {
        dg = (lane < cnt) ? degi[base + lane] : 0;
        incl = dg;
#pragma unroll
        for (int off = 1; off < 64; off <<= 1) {
            const int y = __shfl_up(incl, off);
            if (lane >= off) incl += y;
        }
        const int tot = __shfl(incl, 63);
        if (lane == 0) gsum[b] = tot;
    }
    gridbar(bar, 0);

    // ---- B2: global prefix, write rowptr/fill/dinv; then h0p ----
    if (wave == 0) {
        int v[8];
        int loc = 0;
#pragma unroll
        for (int j = 0; j < 8; j++) { v[j] = gsum[lane * 8 + j]; loc += v[j]; }
        int incg = loc;
#pragma unroll
        for (int off = 1; off < 64; off <<= 1) {
            const int y = __shfl_up(incg, off);
            if (lane >= off) incg += y;
        }
        int cand = incg - loc;
        const int bo = b & 7;
#pragma unroll
        for (int j = 0; j < 8; j++) if (j < bo) cand += v[j];
        const int blockOff = __shfl(cand, b >> 3);
        if (lane < cnt) {
            const int n = base + lane;
            const int r = blockOff + (incl - dg);
            rowptr[n] = r;
            fill[n]   = r;
            const float dv = rsqrtf((float)(dg + 1));
            dinv[n]  = dv;
            dinvS[lane] = dv;
        }
        if (b == 0 && lane == 0) rowptr[N_NODES] = NEDGE;
    }
    __syncthreads();
    for (int idx = tid; idx < cnt * HID; idx += 256) {
        const int ln = idx >> 4;
        const int g = (base + ln) * HID + (idx & 15);
        h0p[g] = h0[g] * dinvS[ln];
    }
    gridbar(bar, 1);

    // ---- C: CSR bucket ----
    for (int e = b * EPB2 + tid; e < (b + 1) * EPB2; e += 256) {
        const int d = dst[e];
        const int pos = atomicAdd(&fill[d], 1);
        srcb[pos] = src[e];
    }
    gridbar(bar, 2);

    // ---- D: gather1 + W1 + relu + W2 -> t2p4 ----
    {
        const int sub = tid & 15;
        const int e4  = sub >> 2;
        const int l4  = sub & 3;
#pragma unroll
        for (int r = 0; r < 4; r++) {
            const int ln = r * 16 + (tid >> 4);
            const int node = base + ln;
            if (ln < cnt) {
                const int beg = rowptr[node], end = rowptr[node + 1];
                f32x4 acc = {0.f, 0.f, 0.f, 0.f};
                if (e4 == 0) acc = *(const f32x4*)(h0p + node * HID + l4 * 4);
                for (int i = beg + e4; i < end; i += 4) {
                    const int s = srcb[i];
                    acc += *(const f32x4*)(h0p + s * HID + l4 * 4);
                }
#pragma unroll
                for (int c = 0; c < 4; c++) {
                    acc[c] += __shfl_xor(acc[c], 4);
                    acc[c] += __shfl_xor(acc[c], 8);
                }
                const int tb = (tid & 63) & ~3;
                float y = 0.f;
#pragma unroll
                for (int i = 0; i < 16; i++) {
                    const float a = __shfl(acc[i & 3], tb | (i >> 2));
                    y = fmaf(a, w1s[i * 16 + sub], y);
                }
                const float dv = dinvS[ln];
                const float h = fmaxf(b1s[sub] + dv * y, 0.f);
                float d0 = h * w2s[sub * 3 + 0];
                float d1 = h * w2s[sub * 3 + 1];
                float d2 = h * w2s[sub * 3 + 2];
#pragma unroll
                for (int msk = 1; msk < 16; msk <<= 1) {
                    d0 += __shfl_xor(d0, msk);
                    d1 += __shfl_xor(d1, msk);
                    d2 += __shfl_xor(d2, msk);
                }
                if (sub < 3) {
                    const float dval = (sub == 0) ? d0 : (sub == 1) ? d1 : d2;
                    t2p4[node * 4 + sub] = dval * dv;
                }
            }
        }
    }
    gridbar(bar, 3);

    // ---- E: gather2 + bias + log_softmax ----
    {
        const int ln = tid >> 2;
        const int node = base + ln;
        if (ln < cnt) {
            const int l = tid & 3;
            const int beg = rowptr[node], end = rowptr[node + 1];
            f32x4 acc = {0.f, 0.f, 0.f, 0.f};
            if (l == 0) acc = *(const f32x4*)(t2p4 + node * 4);
            for (int i = beg + l; i < end; i += 4) {
                const int s = srcb[i];
                acc += *(const f32x4*)(t2p4 + s * 4);
            }
#pragma unroll
            for (int c = 0; c < 3; c++) {
                acc[c] += __shfl_xor(acc[c], 1);
                acc[c] += __shfl_xor(acc[c], 2);
            }
            const float dv = dinvS[ln];
            const float z0 = b2g[0] + dv * acc[0];
            const float z1 = b2g[1] + dv * acc[1];
            const float z2 = b2g[2] + dv * acc[2];
            const float m = fmaxf(z0, fmaxf(z1, z2));
            const float lg = m + logf(expf(z0 - m) + expf(z1 - m) + expf(z2 - m));
            if (l < 3) {
                const float z = (l == 0) ? z0 : (l == 1) ? z1 : z2;
                out[node * 3 + l] = z - lg;
            }
        }
    }
}

extern "C" void kernel_launch(void* const* d_in, const int* in_sizes, int n_in,
                              void* d_out, int out_size, void* d_ws, size_t ws_size,
                              hipStream_t stream)
{
    const float* x   = (const float*)d_in[0];
    const float* w1  = (const float*)d_in[1];
    const float* b1  = (const float*)d_in[2];
    const float* w2  = (const float*)d_in[3];
    const float* b2  = (const float*)d_in[4];
    const float* g1w = (const float*)d_in[5];
    const float* g1b = (const float*)d_in[6];
    const float* g2w = (const float*)d_in[7];
    const float* g2b = (const float*)d_in[8];
    const int*   ei  = (const int*)d_in[9];
    const int* src = ei;
    const int* dst = ei + NEDGE;

    float* ws      = (float*)d_ws;
    float* h0      = ws;                       // 480000 f (dead after h0p build)
    float* t2p4    = ws;                       // 120000 f (aliases dead h0)
    float* h0p     = ws + 480000;              // 480000 f
    float* dinv    = ws + 960000;              // 30000 f
    int*   rowptr  = (int*)(ws + 990000);      // 30001 i (+pad)
    int*   fill    = (int*)(ws + 1020004);     // 30000 i
    int*   degi    = (int*)(ws + 1050004);     // 30000 i
    int*   srcb    = (int*)(ws + 1080004);     // 960000 i
    short* bfragsG = (short*)(ws + 2040004);   // 1024 s = 512 f
    int*   gsum    = (int*)(ws + 2040516);     // 512 i
    int*   bar     = (int*)(ws + 2041028);     // 8 i
    float* out     = (float*)d_out;

    setup_kernel<<<120, 256, 0, stream>>>(w2, bfragsG, degi, bar);
    conv_fused<<<N_NODES, 256, 0, stream>>>(x, w1, b1, b2, bfragsG, dst, degi, h0);
    gcn_mega<<<NB, 256, 0, stream>>>(src, dst, degi, h0, h0p, dinv,
                                     rowptr, fill, srcb,
                                     g1w, g1b, g2w, g2b, t2p4, out, gsum, bar);
}